// Round 8
// baseline (67.874 us; speedup 1.0000x reference)
//
#include <hip/hip_runtime.h>
#include <hip/hip_fp16.h>

// ---------------------------------------------------------------------------
// DotProductAttention: O = softmax((Q K^T / sqrt(128)) * p_q * p_k^T) V
// B=16, S=2048, D=128, fp32 in/out.
// Fold scale*p_q*log2(e) into Q, p_k into K (exact rank-1 folds), cast fp16,
// flash-attention with swapped-QK^T 32x32x16 MFMAs in log2-softmax domain.
// Round 8: amortize per-iter overhead. 256-q blocks (8 waves x 32q), each
// wave processes the FULL 64-key tile (32 MFMAs/iter/wave, r1 inner loop);
// key range split-K x2 (kh halves) keeps grid=256 = 1 block/CU @ 2 waves/SIMD.
// fp16 partial means + (m,l) per row; merge2 combines the halves exactly.
// launch_bounds(512,2) -> 256-VGPR cap (r6's spill was the (512,4) 128 cap).
// ---------------------------------------------------------------------------

typedef _Float16 f16x8 __attribute__((ext_vector_type(8)));
typedef float f32x16 __attribute__((ext_vector_type(16)));
typedef unsigned int u32x4 __attribute__((ext_vector_type(4)));

#define S_LEN 2048
#define DD 128
#define TILE_BYTES 16384     // 64 keys x 128 d x 2B (one image tile)
#define NT 32                // kv tiles of 64 keys per batch
#define NTH 16               // tiles per key-half (split-K factor 2)
#define PART_ROWS 32768      // 16 batches * 2048 q-rows
#define PART_STRIDE 4194304  // PART_ROWS * 128 elems per kh slab

#define EXP2(x) __builtin_amdgcn_exp2f(x)   // raw v_exp_f32 (2^x)

__device__ __forceinline__ unsigned int pk2(float a, float b) {
  __half2 h = __float22half2_rn(make_float2(a, b));
  return __builtin_bit_cast(unsigned int, h);
}

__device__ __forceinline__ void st8(void* dst, const float v[8]) {
  u32x4 u;
  u[0] = pk2(v[0], v[1]);
  u[1] = pk2(v[2], v[3]);
  u[2] = pk2(v[4], v[5]);
  u[3] = pk2(v[6], v[7]);
  *(u32x4*)dst = u;
}

__device__ __forceinline__ void gld16(const void* g, void* l) {
  __builtin_amdgcn_global_load_lds(
      (const __attribute__((address_space(1))) unsigned int*)g,
      (__attribute__((address_space(3))) unsigned int*)l, 16, 0, 0);
}

// --------------------------- pre-pass: Q --------------------------------
// Q' = fp16(Q * (log2e/sqrt(128)) * p_q[row]); row-major [B*S][128]
__global__ __launch_bounds__(256) void prep_q_k(const float* __restrict__ Q,
                                                const float* __restrict__ pq,
                                                char* __restrict__ qh) {
  size_t i = ((size_t)blockIdx.x * 256 + threadIdx.x) * 8;
  const float g = pq[i >> 7] * 0.12751743343158394f;  // (1/sqrt(128))*log2(e)
  float4 a = *(const float4*)(Q + i);
  float4 b = *(const float4*)(Q + i + 4);
  float v[8] = {a.x * g, a.y * g, a.z * g, a.w * g,
                b.x * g, b.y * g, b.z * g, b.w * g};
  st8(qh + i * 2, v);
}

// --------------------------- pre-pass: K,V images ------------------------
// K image tile (64x128): byte(key,d) = key*256 + ((2d) ^ ((key&7)<<4))
// V image tile:          byte(key,d) = d*128 + ((2key) ^ ((d&7)<<4))
__global__ __launch_bounds__(256) void prep_kv(
    const float* __restrict__ K, const float* __restrict__ V,
    const float* __restrict__ pk, char* __restrict__ kimg,
    char* __restrict__ vimg) {
  __shared__ float vt[64 * 132];
  const int t = threadIdx.x;
  const int bid = blockIdx.x;
  const int bq = bid & 15;
  const int kt = bid >> 4;
  const size_t rowbase = (size_t)bq * S_LEN + kt * 64;

  // stage V tile (fp32) into padded LDS for the transpose
#pragma unroll
  for (int cc = 0; cc < 8; ++cc) {
    const int f = cc * 256 + t;
    const int row = f >> 5;
    const int col = (f & 31) * 4;
    *(float4*)(vt + row * 132 + col) = *(const float4*)(V + (rowbase + row) * DD + col);
  }

  // K image: pure global->global, fold p_k
  char* kdst = kimg + (size_t)(bq * NT + kt) * TILE_BYTES;
#pragma unroll
  for (int cc = 0; cc < 4; ++cc) {
    const int p0 = (cc * 256 + t) * 16;
    const int key = p0 >> 8;
    const int d0 = ((p0 & 255) ^ ((key & 7) << 4)) >> 1;
    const float g = pk[rowbase + key];
    const float* src = K + (rowbase + key) * DD + d0;
    float4 a = *(const float4*)(src);
    float4 b = *(const float4*)(src + 4);
    float v[8] = {a.x * g, a.y * g, a.z * g, a.w * g,
                  b.x * g, b.y * g, b.z * g, b.w * g};
    st8(kdst + p0, v);
  }

  __syncthreads();

  // V image from LDS transpose
  char* vdst = vimg + (size_t)(bq * NT + kt) * TILE_BYTES;
#pragma unroll
  for (int cc = 0; cc < 4; ++cc) {
    const int p0 = (cc * 256 + t) * 16;
    const int dcol = p0 >> 7;
    const int key0 = ((p0 & 127) ^ ((dcol & 7) << 4)) >> 1;
    float v[8];
#pragma unroll
    for (int j = 0; j < 8; ++j) v[j] = vt[(key0 + j) * 132 + dcol];
    st8(vdst + p0, v);
  }
}

// --------------------------- main attention ------------------------------
// 512 threads = 8 waves; wave qs owns 32 q-rows (q0 = qt*256 + qs*32) and
// processes the FULL 64-key tile per iter (s0: keys 0-31, s1: keys 32-63).
// Block covers key range [kh*1024, (kh+1)*1024). Emits fp16 partial means
// + (m,l) per q-row; merge2 combines the two kh halves exactly.
__global__ __launch_bounds__(512, 2) void attn_main(const char* __restrict__ qh,
                                                    const char* __restrict__ kimg,
                                                    const char* __restrict__ vimg,
                                                    _Float16* __restrict__ part,
                                                    float2* __restrict__ mlws) {
  __shared__ float4 ldsraw[4096];  // 65536 B: 2 x (16KB K + 16KB V) dbuf; T aliases
  char* lds = (char*)ldsraw;
  const int tid = threadIdx.x;
  const int qs = tid >> 6;   // wave = q subtile 0..7
  const int lane = tid & 63;
  const int c = lane & 31;
  const int h = lane >> 5;
  const int swz = (c & 7) << 4;
  const int bid = blockIdx.x;
  const int bq = 2 * (bid & 7) + ((bid >> 3) & 1);  // batch pinned to XCD
  const int qt = (bid >> 4) & 7;                    // q-tile (256 rows) 0..7
  const int kh = bid >> 7;                          // key-half 0..1
  const int q0 = qt * 256 + qs * 32;

  // Q fragments (B-operand of swapped QK^T): lane c = q row, 8 d's per kc
  f16x8 qf[8];
  const char* qrow = qh + (size_t)(bq * S_LEN + q0 + c) * (DD * 2);
#pragma unroll
  for (int kc = 0; kc < 8; ++kc) qf[kc] = *(const f16x8*)(qrow + kc * 32 + h * 16);

  f32x16 acc[4];
#pragma unroll
  for (int d = 0; d < 4; ++d) {
#pragma unroll
    for (int r = 0; r < 16; ++r) acc[d][r] = 0.f;
  }
  float m_run = -1.0e30f, l_run = 0.f;

  const char* kb = kimg + (size_t)(bq * NT + kh * NTH) * TILE_BYTES;
  const char* vb = vimg + (size_t)(bq * NT + kh * NTH) * TILE_BYTES;

  // prologue: stage tile 0 into buffer 0 (linear copy of pre-swizzled image)
#pragma unroll
  for (int j = 0; j < 2; ++j) {
    gld16(kb + j * 8192 + tid * 16, lds + j * 8192 + tid * 16);
    gld16(vb + j * 8192 + tid * 16, lds + TILE_BYTES + j * 8192 + tid * 16);
  }

  for (int kt = 0; kt < NTH; ++kt) {
    __syncthreads();  // drains staging vmcnt; frees other buffer
    const int cur = (kt & 1) << 15;
    if (kt + 1 < NTH) {
      const int nxt = ((kt + 1) & 1) << 15;
      const char* kn = kb + (size_t)(kt + 1) * TILE_BYTES;
      const char* vn = vb + (size_t)(kt + 1) * TILE_BYTES;
#pragma unroll
      for (int j = 0; j < 2; ++j) {
        gld16(kn + j * 8192 + tid * 16, lds + nxt + j * 8192 + tid * 16);
        gld16(vn + j * 8192 + tid * 16, lds + nxt + TILE_BYTES + j * 8192 + tid * 16);
      }
    }
    const char* kl = lds + cur;
    const char* vl = lds + cur + TILE_BYTES;

    // S^T = K' Q'^T over the FULL 64-key tile (two 32-key subtiles)
    f32x16 s0, s1;
#pragma unroll
    for (int r = 0; r < 16; ++r) { s0[r] = 0.f; s1[r] = 0.f; }
    __builtin_amdgcn_s_setprio(1);
#pragma unroll
    for (int kc = 0; kc < 8; ++kc) {
      f16x8 k0 = *(const f16x8*)(kl + c * 256 + ((kc * 32 + h * 16) ^ swz));
      f16x8 k1 = *(const f16x8*)(kl + (32 + c) * 256 + ((kc * 32 + h * 16) ^ swz));
      s0 = __builtin_amdgcn_mfma_f32_32x32x16_f16(k0, qf[kc], s0, 0, 0, 0);
      s1 = __builtin_amdgcn_mfma_f32_32x32x16_f16(k1, qf[kc], s1, 0, 0, 0);
    }
    __builtin_amdgcn_s_setprio(0);

    // lane-local online softmax (log2 domain; row q = c), 64-key tile
    float m0 = fmaxf(fmaxf(s0[0], s0[1]), fmaxf(s0[2], s0[3]));
    float m1 = fmaxf(fmaxf(s0[4], s0[5]), fmaxf(s0[6], s0[7]));
    float m2 = fmaxf(fmaxf(s0[8], s0[9]), fmaxf(s0[10], s0[11]));
    float m3 = fmaxf(fmaxf(s0[12], s0[13]), fmaxf(s0[14], s0[15]));
    float m4 = fmaxf(fmaxf(s1[0], s1[1]), fmaxf(s1[2], s1[3]));
    float m5 = fmaxf(fmaxf(s1[4], s1[5]), fmaxf(s1[6], s1[7]));
    float m6 = fmaxf(fmaxf(s1[8], s1[9]), fmaxf(s1[10], s1[11]));
    float m7 = fmaxf(fmaxf(s1[12], s1[13]), fmaxf(s1[14], s1[15]));
    m0 = fmaxf(m0, m1); m2 = fmaxf(m2, m3); m4 = fmaxf(m4, m5); m6 = fmaxf(m6, m7);
    float cm = fmaxf(fmaxf(m0, m2), fmaxf(m4, m6));
    cm = fmaxf(cm, __shfl_xor(cm, 32));
    if (__any(cm > m_run + 11.0f)) {  // defer-max: rescale only on real growth
      const float mn = fmaxf(m_run, cm);
      const float al = EXP2(m_run - mn);
      m_run = mn;
      l_run *= al;
#pragma unroll
      for (int d = 0; d < 4; ++d) {
#pragma unroll
        for (int r = 0; r < 16; ++r) acc[d][r] *= al;
      }
    }
    float ps0 = 0.f, ps1 = 0.f;
#pragma unroll
    for (int r = 0; r < 16; ++r) {
      s0[r] = EXP2(s0[r] - m_run); ps0 += s0[r];
      s1[r] = EXP2(s1[r] - m_run); ps1 += s1[r];
    }
    l_run += ps0 + ps1;

    // PV: O^T += V^T P^T over four 16-key chunks (P^T built in-register)
#pragma unroll
    for (int kc = 0; kc < 4; ++kc) {
      const f32x16 pn = (kc < 2) ? s0 : s1;   // folds at unroll
      const int A = (kc & 1) * 8;
      const int Bb = A + 4;
      unsigned pA0 = pk2(pn[A + 0], pn[A + 1]);
      unsigned pA1 = pk2(pn[A + 2], pn[A + 3]);
      unsigned pB0 = pk2(pn[Bb + 0], pn[Bb + 1]);
      unsigned pB1 = pk2(pn[Bb + 2], pn[Bb + 3]);
      unsigned own0 = h ? pB0 : pA0;
      unsigned own1 = h ? pB1 : pA1;
      unsigned snd0 = h ? pA0 : pB0;
      unsigned snd1 = h ? pA1 : pB1;
      unsigned rcv0 = __shfl_xor(snd0, 32);
      unsigned rcv1 = __shfl_xor(snd1, 32);
      u32x4 pw;
      pw[0] = h ? rcv0 : own0;  // elems 0,1 (source half h=0)
      pw[1] = h ? rcv1 : own1;  // elems 2,3
      pw[2] = h ? own0 : rcv0;  // elems 4,5 (source half h=1)
      pw[3] = h ? own1 : rcv1;  // elems 6,7
      f16x8 pf = __builtin_bit_cast(f16x8, pw);
      __builtin_amdgcn_s_setprio(1);
#pragma unroll
      for (int d = 0; d < 4; ++d) {
        f16x8 vf = *(const f16x8*)(vl + (d * 32 + c) * 128 + ((kc * 32 + h * 16) ^ swz));
        acc[d] = __builtin_amdgcn_mfma_f32_32x32x16_f16(vf, pf, acc[d], 0, 0, 0);
      }
      __builtin_amdgcn_s_setprio(0);
    }
  }

  // ---- epilogue: finalize partial mean, transpose via LDS (fp16), store ----
  l_run += __shfl_xor(l_run, 32);  // full tile-range sum for row q=c
  const float w = 1.0f / l_run;    // partial MEAN normalization for this kh

  __syncthreads();  // all waves done with stage buffers
  char* T = lds;    // 256 q x 128 d fp16 (64KB), swizzled rows
#pragma unroll
  for (int d = 0; d < 4; ++d) {
#pragma unroll
    for (int rr = 0; rr < 4; ++rr) {
      // regs rr*4+j are O^T rows dd = d*32 + rr*8 + j + 4h (j=0..3)
      unsigned lo = pk2(acc[d][rr * 4 + 0] * w, acc[d][rr * 4 + 1] * w);
      unsigned hi = pk2(acc[d][rr * 4 + 2] * w, acc[d][rr * 4 + 3] * w);
      const int byte = (qs * 32 + c) * 256 + ((d * 64 + rr * 16 + h * 8) ^ swz);
      uint2 u; u.x = lo; u.y = hi;
      *(uint2*)(T + byte) = u;
    }
  }
  if (h == 0)
    mlws[(size_t)kh * PART_ROWS + (size_t)bq * S_LEN + qt * 256 + qs * 32 + c] =
        make_float2(m_run, l_run);
  __syncthreads();

  // coalesced copy T -> part[kh] (un-swizzle)
  _Float16* pdst = part + (size_t)kh * PART_STRIDE +
                   ((size_t)bq * S_LEN + qt * 256) * 128;
#pragma unroll
  for (int p = 0; p < 8; ++p) {
    const int idx = p * 512 + tid;
    const int q = idx >> 4;
    const int o16 = (idx & 15) * 16;  // byte offset of 16B chunk within row
    u32x4 v = *(const u32x4*)(T + q * 256 + (o16 ^ ((q & 7) << 4)));
    *(u32x4*)(pdst + q * 128 + (idx & 15) * 8) = v;
  }
}

// --------------------------- split-K merge --------------------------------
// O[r][d] = (p0*l0*2^(m0-M) + p1*l1*2^(m1-M)) / (l0*2^(m0-M) + l1*2^(m1-M))
__global__ __launch_bounds__(256) void merge2(const _Float16* __restrict__ part,
                                              const float2* __restrict__ mlws,
                                              float* __restrict__ out) {
  const int t = blockIdx.x * 256 + threadIdx.x;
  const int d0 = (t & 15) * 8;
  const int r = t >> 4;  // global row = b*2048 + q
  const float2 a = mlws[r];
  const float2 b = mlws[PART_ROWS + r];
  const float M = fmaxf(a.x, b.x);
  const float wa = a.y * EXP2(a.x - M);
  const float wb = b.y * EXP2(b.x - M);
  const float inv = 1.f / (wa + wb);
  const float fa = wa * inv, fb = wb * inv;
  const f16x8 pa = *(const f16x8*)(part + (size_t)r * 128 + d0);
  const f16x8 pb = *(const f16x8*)(part + PART_STRIDE + (size_t)r * 128 + d0);
  float4 o0, o1;
  o0.x = fa * (float)pa[0] + fb * (float)pb[0];
  o0.y = fa * (float)pa[1] + fb * (float)pb[1];
  o0.z = fa * (float)pa[2] + fb * (float)pb[2];
  o0.w = fa * (float)pa[3] + fb * (float)pb[3];
  o1.x = fa * (float)pa[4] + fb * (float)pb[4];
  o1.y = fa * (float)pa[5] + fb * (float)pb[5];
  o1.z = fa * (float)pa[6] + fb * (float)pb[6];
  o1.w = fa * (float)pa[7] + fb * (float)pb[7];
  float* orow = out + (size_t)r * 128 + d0;
  *(float4*)orow = o0;
  *(float4*)(orow + 4) = o1;
}

// --------------------------- launcher ------------------------------------
extern "C" void kernel_launch(void* const* d_in, const int* in_sizes, int n_in,
                              void* d_out, int out_size, void* d_ws, size_t ws_size,
                              hipStream_t stream) {
  const float* Q = (const float*)d_in[0];
  const float* K = (const float*)d_in[1];
  const float* V = (const float*)d_in[2];
  const float* pq = (const float*)d_in[3];
  const float* pk = (const float*)d_in[4];
  float* out = (float*)d_out;
  char* ws = (char*)d_ws;
  char* qh = ws;                                   // 8 MB fp16 scaled Q
  char* kimg = ws + (8u << 20);                    // 8 MB K image (gated, swizzled)
  char* vimg = ws + (16u << 20);                   // 8 MB V image (transposed, swizzled)
  _Float16* part = (_Float16*)(ws + (24u << 20));  // 16 MB fp16 partial means (2 slabs)
  float2* mlws = (float2*)(ws + (42u << 20));      // 0.5 MB (m,l) per row per slab

  prep_q_k<<<2048, 256, 0, stream>>>(Q, pq, qh);
  prep_kv<<<512, 256, 0, stream>>>(K, V, pk, kimg, vimg);
  attn_main<<<256, 512, 0, stream>>>(qh, kimg, vimg, part, mlws);
  merge2<<<2048, 256, 0, stream>>>(part, mlws, out);
}